// Round 16
// baseline (63.793 us; speedup 1.0000x reference)
//
#include <hip/hip_runtime.h>
#include <math.h>

#define BB 16
#define NN 8192
#define MM 64
#define ROW 85
#define EPS_F 1e-7f

#define NT1 256
#define NT2 1024         // 16 waves
#define NW  16
#define CPW 4            // clusters per wave
#define CAPB 8           // LDS-cached kept entries per cluster (overflow -> exact global walk)

typedef unsigned long long u64;

// ---------------- Kernel 1: boxes + masked score keys (cluster-permuted) ----------------
__global__ void prep_kernel(const float* __restrict__ outp,
                            const float* __restrict__ lab,
                            float4* __restrict__ boxes,
                            float* __restrict__ keys) {
    __shared__ float4 gbox[MM];
    __shared__ float garea[MM];
    const int b = blockIdx.x;
    const int tid = threadIdx.x;
    if (tid < MM) {
        const float* lr = lab + ((size_t)b * MM + tid) * 5;
        float cx = lr[1], cy = lr[2], w = lr[3], h = lr[4];
        float x1 = fminf(fmaxf(cx - w * 0.5f, 0.f), 1.f) * 640.f;
        float y1 = fminf(fmaxf(cy - h * 0.5f, 0.f), 1.f) * 640.f;
        float x2 = fminf(fmaxf(cx + w * 0.5f, 0.f), 1.f) * 640.f;
        float y2 = fminf(fmaxf(cy + h * 0.5f, 0.f), 1.f) * 640.f;
        gbox[tid] = make_float4(x1, y1, x2, y2);
        garea[tid] = (x2 - x1) * (y2 - y1);
    }
    __syncthreads();
    const int n = blockIdx.y * NT1 + tid;
    const float* row = outp + ((size_t)b * NN + n) * ROW;
    float cx = row[0], cy = row[1], w = row[2], h = row[3];
    float obj = row[4], c0 = row[5];
    float px1 = cx - w * 0.5f, py1 = cy - h * 0.5f;
    float px2 = cx + w * 0.5f, py2 = cy + h * 0.5f;
    float pa = (px2 - px1) * (py2 - py1);

    const int m0 = n & (MM - 1);
    bool match;
    {
        float4 g = gbox[m0];
        float iw = fmaxf(fminf(px2, g.z) - fmaxf(px1, g.x), 0.f);
        float ih = fmaxf(fminf(py2, g.w) - fmaxf(py1, g.y), 0.f);
        float inter = iw * ih;
        match = (inter / (garea[m0] + pa - inter) >= 0.5f);  // exact div as reference
    }
    if (!match) {
        for (int m = 0; m < MM; ++m) {
            float4 g = gbox[m];
            float iw = fmaxf(fminf(px2, g.z) - fmaxf(px1, g.x), 0.f);
            float ih = fmaxf(fminf(py2, g.w) - fmaxf(py1, g.y), 0.f);
            float inter = iw * ih;
            match = match || (inter / (garea[m] + pa - inter) >= 0.5f);
        }
    }
    bool valid = (obj >= 0.0f) && match;
    // cluster permutation: ppos = (n%64)*128 + n/64
    size_t bn = (size_t)b * NN + ((n & 63) * 128 + (n >> 6));
    boxes[bn] = make_float4(px1, py1, px2, py2);
    keys[bn] = valid ? (c0 * obj) : -INFINITY;
}

// ---------------- DPP wave folds (valid at lane 63) ----------------
__device__ __forceinline__ float wave_fold_max(float x) {
#define DPP_STEPX(ctrl)                                                          \
    { int _o = __builtin_amdgcn_update_dpp(__float_as_int(x), __float_as_int(x), \
                                           (ctrl), 0xF, 0xF, false);             \
      x = fmaxf(x, __int_as_float(_o)); }
    DPP_STEPX(0x111) DPP_STEPX(0x112) DPP_STEPX(0x114)
    DPP_STEPX(0x118) DPP_STEPX(0x142) DPP_STEPX(0x143)
#undef DPP_STEPX
    return x;
}
__device__ __forceinline__ float wave_fold_min(float x) {
#define DPP_STEPN(ctrl)                                                          \
    { int _o = __builtin_amdgcn_update_dpp(__float_as_int(x), __float_as_int(x), \
                                           (ctrl), 0xF, 0xF, false);             \
      x = fminf(x, __int_as_float(_o)); }
    DPP_STEPN(0x111) DPP_STEPN(0x112) DPP_STEPN(0x114)
    DPP_STEPN(0x118) DPP_STEPN(0x142) DPP_STEPN(0x143)
#undef DPP_STEPN
    return x;
}
__device__ __forceinline__ float wave_max64(float x) {
    return __int_as_float(__builtin_amdgcn_readlane(__float_as_int(wave_fold_max(x)), 63));
}
__device__ __forceinline__ float wave_sum64(float x) {
#define DPP_ADD(ctrl)                                                            \
    { int _o = __builtin_amdgcn_update_dpp(0, __float_as_int(x),                 \
                                           (ctrl), 0xF, 0xF, true);              \
      x += __int_as_float(_o); }
    DPP_ADD(0x111) DPP_ADD(0x112) DPP_ADD(0x114)
    DPP_ADD(0x118) DPP_ADD(0x142) DPP_ADD(0x143)
#undef DPP_ADD
    return __int_as_float(__builtin_amdgcn_readlane(__float_as_int(x), 63));
}
__device__ __forceinline__ float bcastlane(float v, int l) {
    return __int_as_float(__builtin_amdgcn_readlane(__float_as_int(v), l));
}

// kill test: kept box (sj, bj, hbj) vs my member slot K_
#define KILL_TEST(AK, K_)  do {                                                  \
    float _xx1 = fmaxf(bj.x, lx1[K_]), _yy1 = fmaxf(bj.y, ly1[K_]);              \
    float _xx2 = fminf(bj.z, lx2[K_]), _yy2 = fminf(bj.w, ly2[K_]);              \
    float _iw = fmaxf(_xx2 - _xx1 + 1.f, 0.f);                                   \
    float _ih = fmaxf(_yy2 - _yy1 + 1.f, 0.f);                                   \
    float _in = _iw * _ih;                                                       \
    if (sj > lps[K_] && 1.5f * _in > hbj + lha[K_]) (AK) = -INFINITY;            \
} while (0)

// Δ-screen push: broadcast each Δ-member, lane-parallel screen vs all cluster bbs
#define PUSH_DELTA(DD, SLOT) do {                                                \
    u64 _dd = (DD);                                                              \
    while (_dd) {                                                                \
        int _j = __ffsll(_dd) - 1; _dd &= (_dd - 1);                             \
        float _ex1 = bcastlane(lx1[SLOT], _j), _ey1 = bcastlane(ly1[SLOT], _j);  \
        float _ex2 = bcastlane(lx2[SLOT], _j), _ey2 = bcastlane(ly2[SLOT], _j);  \
        float _eha = bcastlane(lha[SLOT], _j);                                   \
        float _iwp = fminf(_ex2, tbL.z) - fmaxf(_ex1, tbL.x) + 1.f;              \
        float _ihp = fminf(_ey2, tbL.w) - fmaxf(_ey1, tbL.y) + 1.f;              \
        bool _hit = (_iwp > 0.f) && (_ihp > 0.f) &&                              \
                    (1.5f * (_iwp * _ihp) > _eha + 0.5f * EPS_F + tmhaL);        \
        targets |= __ballot(_hit);                                               \
    }                                                                            \
} while (0)

// full stateless cluster recompute: read parity `par`, write `parN`, push dirt
#define DO_CLUSTER(C_) do {                                                      \
    const int c = (C_);                                                          \
    /* issue member loads first (consumed after the screen) */                   \
    int _i0 = c * 128 + lane;                                                    \
    float4 _bb0 = boxes[base + _i0];                                             \
    float4 _bb1 = boxes[base + _i0 + 64];                                        \
    float  _k0  = keys[base + _i0];                                              \
    float  _k1  = keys[base + _i0 + 64];                                         \
    u64 om0 = kMask0[par][c], om1 = kMask1[par][c];                              \
    float4 CBc = clusterBB[c];                                                   \
    float mha = 0.5f * clusterMinA[c];                                           \
    /* lane-parallel screen (LDS only; loads still in flight) */                 \
    bool _flag = false;                                                          \
    {                                                                            \
        const u64 _adjc = adjL[c];                                               \
        if ((_adjc >> lane) & 1ull) {                                            \
            int _K = keptCnt[par][lane];                                         \
            if (_K > CAPB) _flag = true;                                         \
            int _KB = _K < CAPB ? _K : CAPB;                                     \
            _Pragma("unroll 4")                                                  \
            for (int _t2 = 0; _t2 < _KB; ++_t2) {                                \
                float4 _bj = keptBoxL[par][lane][_t2];                           \
                float2 _mt = keptMetaL[par][lane][_t2];                          \
                float _iwS = fminf(_bj.z, CBc.z) - fmaxf(_bj.x, CBc.x) + 1.f;    \
                float _ihS = fminf(_bj.w, CBc.w) - fmaxf(_bj.y, CBc.y) + 1.f;    \
                if (_iwS > 0.f && _ihS > 0.f && 1.5f * (_iwS * _ihS) > _mt.y + mha) \
                    _flag = true;                                                \
            }                                                                    \
        }                                                                        \
    }                                                                            \
    u64 passM = __ballot(_flag);                                                 \
    /* unpack prefetched members */                                              \
    float lx1[2] = { _bb0.x, _bb1.x }, ly1[2] = { _bb0.y, _bb1.y };              \
    float lx2[2] = { _bb0.z, _bb1.z }, ly2[2] = { _bb0.w, _bb1.w };              \
    float lps[2] = { _k0, _k1 };                                                 \
    float lha[2] = { 0.5f * ((lx2[0] - lx1[0] + 1.f) * (ly2[0] - ly1[0] + 1.f)), \
                     0.5f * ((lx2[1] - lx1[1] + 1.f) * (ly2[1] - ly1[1] + 1.f)) };\
    float a0 = lps[0], a1 = lps[1];                                              \
    /* serial walk over passing neighbors */                                     \
    while (passM) {                                                              \
        int ac = __ffsll(passM) - 1; passM &= (passM - 1);                       \
        int K = keptCnt[par][ac];                                                \
        int KB = K < CAPB ? K : CAPB;                                            \
        _Pragma("unroll 4")                                                      \
        for (int t2 = 0; t2 < KB; ++t2) {                                        \
            float4 bj = keptBoxL[par][ac][t2];                                   \
            float2 mt = keptMetaL[par][ac][t2];                                  \
            float iwS = fminf(bj.z, CBc.z) - fmaxf(bj.x, CBc.x) + 1.f;           \
            float ihS = fminf(bj.w, CBc.w) - fmaxf(bj.y, CBc.y) + 1.f;           \
            if (iwS > 0.f && ihS > 0.f && 1.5f * (iwS * ihS) > mt.y + mha) {     \
                float sj = mt.x, hbj = mt.y;                                     \
                KILL_TEST(a0, 0);                                                \
                KILL_TEST(a1, 1);                                                \
            }                                                                    \
        }                                                                        \
        if (K > CAPB) {                      /* exact overflow (rare) */         \
            u64 mm = kMask0[par][ac];                                            \
            while (mm) {                                                         \
                int bit = __ffsll(mm) - 1; mm &= (mm - 1);                       \
                int gi = ac * 128 + bit;                                         \
                float4 bj = boxes[base + gi];                                    \
                float sj = keys[base + gi];                                      \
                float hbj = 0.5f * ((bj.z - bj.x + 1.f) * (bj.w - bj.y + 1.f))   \
                            + 0.5f * EPS_F;                                      \
                KILL_TEST(a0, 0);                                                \
                KILL_TEST(a1, 1);                                                \
            }                                                                    \
            mm = kMask1[par][ac];                                                \
            while (mm) {                                                         \
                int bit = __ffsll(mm) - 1; mm &= (mm - 1);                       \
                int gi = ac * 128 + 64 + bit;                                    \
                float4 bj = boxes[base + gi];                                    \
                float sj = keys[base + gi];                                      \
                float hbj = 0.5f * ((bj.z - bj.x + 1.f) * (bj.w - bj.y + 1.f))   \
                            + 0.5f * EPS_F;                                      \
                KILL_TEST(a0, 0);                                                \
                KILL_TEST(a1, 1);                                                \
            }                                                                    \
        }                                                                        \
    }                                                                            \
    /* local serial greedy (wave-local, no barriers); writes go to parN */       \
    bool kept0 = false, kept1 = false;                                           \
    int cnt = 0;                                                                 \
    while (true) {                                                               \
        float lv = fmaxf(a0, a1);                                                \
        float wm = wave_max64(lv);                                               \
        if (wm == -INFINITY) break;                                              \
        u64 bm = __ballot(lv == wm);                                             \
        int wl = __ffsll(bm) - 1;                                                \
        int la = (a0 == lv) ? 0 : 1;                                             \
        float cxa = la ? lx1[1] : lx1[0];                                        \
        float cya = la ? ly1[1] : ly1[0];                                        \
        float cxb = la ? lx2[1] : lx2[0];                                        \
        float cyb = la ? ly2[1] : ly2[0];                                        \
        float cha = la ? lha[1] : lha[0];                                        \
        float bx1 = bcastlane(cxa, wl), by1 = bcastlane(cya, wl);                \
        float bx2 = bcastlane(cxb, wl), by2 = bcastlane(cyb, wl);                \
        float hcb = bcastlane(cha, wl) + 0.5f * EPS_F;                           \
        if (lane == wl) {                                                        \
            if (cnt < CAPB) {                                                    \
                keptBoxL[parN][c][cnt] = make_float4(cxa, cya, cxb, cyb);        \
                keptMetaL[parN][c][cnt] = make_float2(lv, cha + 0.5f * EPS_F);   \
            }                                                                    \
            if (la == 0) { kept0 = true; a0 = -INFINITY; }                       \
            else         { kept1 = true; a1 = -INFINITY; }                       \
        }                                                                        \
        cnt++;                                                                   \
        if (a0 != -INFINITY) {                                                   \
            float xx1 = fmaxf(bx1, lx1[0]), yy1 = fmaxf(by1, ly1[0]);            \
            float xx2 = fminf(bx2, lx2[0]), yy2 = fminf(by2, ly2[0]);            \
            float iw = fmaxf(xx2 - xx1 + 1.f, 0.f);                              \
            float ih = fmaxf(yy2 - yy1 + 1.f, 0.f);                              \
            if (1.5f * (iw * ih) > hcb + lha[0]) a0 = -INFINITY;                 \
        }                                                                        \
        if (a1 != -INFINITY) {                                                   \
            float xx1 = fmaxf(bx1, lx1[1]), yy1 = fmaxf(by1, ly1[1]);            \
            float xx2 = fminf(bx2, lx2[1]), yy2 = fminf(by2, ly2[1]);            \
            float iw = fmaxf(xx2 - xx1 + 1.f, 0.f);                              \
            float ih = fmaxf(yy2 - yy1 + 1.f, 0.f);                              \
            if (1.5f * (iw * ih) > hcb + lha[1]) a1 = -INFINITY;                 \
        }                                                                        \
    }                                                                            \
    u64 m0 = __ballot(kept0);                                                    \
    u64 m1 = __ballot(kept1);                                                    \
    if (lane == 0) {                                                             \
        kMask0[parN][c] = m0; kMask1[parN][c] = m1; keptCnt[parN][c] = cnt;      \
    }                                                                            \
    u64 d0 = m0 ^ om0, d1 = m1 ^ om1;                                            \
    if ((d0 | d1) != 0ull) {                                                     \
        float4 tbL = clusterBB[lane];                                            \
        float tmhaL = 0.5f * clusterMinA[lane];                                  \
        u64 targets = 0ull;                                                      \
        PUSH_DELTA(d0, 0);                                                       \
        PUSH_DELTA(d1, 1);                                                       \
        targets &= adjL[c];                                                      \
        if (lane == 0 && targets) {                                              \
            atomicOr(&dirtyM[nxt][0], (unsigned)(targets & 0xffffffffull));      \
            atomicOr(&dirtyM[nxt][1], (unsigned)(targets >> 32));                \
        }                                                                        \
    }                                                                            \
} while (0)

// copy-forward unchanged cluster state par -> parN (tear-free Jacobi)
#define COPY_CLUSTER(C_) do {                                                    \
    const int c = (C_);                                                          \
    if (lane < CAPB) {                                                           \
        keptBoxL[parN][c][lane] = keptBoxL[par][c][lane];                        \
        keptMetaL[parN][c][lane] = keptMetaL[par][c][lane];                      \
    }                                                                            \
    if (lane == 0) {                                                             \
        kMask0[parN][c] = kMask0[par][c];                                        \
        kMask1[parN][c] = kMask1[par][c];                                        \
        keptCnt[parN][c] = keptCnt[par][c];                                      \
    }                                                                            \
} while (0)

// ---------------- Kernel 2: Δ-push dirty-gated Jacobi greedy NMS ----------------
__global__ void __launch_bounds__(NT2)
nms_kernel(const float4* __restrict__ boxes, const float* __restrict__ keys,
           float* __restrict__ loss) {
    __shared__ float4 clusterBB[MM];
    __shared__ float  clusterMinA[MM];
    __shared__ float  topScore[MM];
    __shared__ int    slotCluster[MM];           // rank r -> cluster id
    __shared__ u64    adjL[MM];
    __shared__ float4 keptBoxL[2][MM][CAPB];     // 16 KB (parity)
    __shared__ float2 keptMetaL[2][MM][CAPB];    //  8 KB (score, halfArea+eps/2)
    __shared__ u64    kMask0[2][MM];
    __shared__ u64    kMask1[2][MM];
    __shared__ int    keptCnt[2][MM];
    __shared__ unsigned int dirtyM[3][2];        // rotating dirty-target masks
    __shared__ float  waveSum[NW];
    __shared__ int    waveCnt[NW];

    const int b = blockIdx.x;
    const int tid = threadIdx.x;
    const int wid = tid >> 6;
    const int lane = tid & 63;
    const size_t base = (size_t)b * NN;

    // ---- step 1: per-cluster stats (no retained member registers) ----
#pragma unroll
    for (int q = 0; q < CPW; ++q) {
        const int c = CPW * wid + q;
        float mx = INFINITY, my = INFINITY, Mx = -INFINITY, My = -INFINITY;
        float mA = INFINITY, tS = -INFINITY;
#pragma unroll
        for (int s = 0; s < 2; ++s) {
            int idx = c * 128 + s * 64 + lane;
            float4 bb = boxes[base + idx];
            float sc = keys[base + idx];
            float ar = (bb.z - bb.x + 1.f) * (bb.w - bb.y + 1.f);
            if (sc != -INFINITY) {
                mx = fminf(mx, bb.x); my = fminf(my, bb.y);
                Mx = fmaxf(Mx, bb.z); My = fmaxf(My, bb.w);
                mA = fminf(mA, ar);   tS = fmaxf(tS, sc);
            }
        }
        mx = wave_fold_min(mx); my = wave_fold_min(my);
        Mx = wave_fold_max(Mx); My = wave_fold_max(My);
        mA = wave_fold_min(mA); tS = wave_fold_max(tS);
        if (lane == 63) {
            clusterBB[c] = make_float4(mx, my, Mx, My);
            clusterMinA[c] = mA;
            topScore[c] = tS;
        }
    }
    __syncthreads();

    // ---- step 2 (wave 0): adjacency + score ranking + state init ----
    if (wid == 0) {
        const int t = lane;
        float4 bbT = clusterBB[t];
        float  maT = clusterMinA[t];
        u64 adj = 0ull;
        for (int j = 0; j < MM; ++j) {
            float4 bbJ = clusterBB[j];
            float  maJ = clusterMinA[j];
            float iw = fminf(bbT.z, bbJ.z) - fmaxf(bbT.x, bbJ.x) + 1.f;
            float ih = fminf(bbT.w, bbJ.w) - fmaxf(bbT.y, bbJ.y) + 1.f;
            if (j != t && iw > 0.f && ih > 0.f) {
                float I = iw * ih;
                // IoU>0.5 between members impossible if 3I < aI+aJ or 2I < max(aI,aJ)
                bool noe = (3.f * I < maT + maJ) || (2.f * I < fmaxf(maT, maJ));
                if (!noe) adj |= (1ull << j);
            }
        }
        adjL[t] = adj;
        kMask0[0][t] = 0ull; kMask1[0][t] = 0ull;
        keptCnt[0][t] = 0;
        // rank by top score descending (tie-break by index)
        float myS = topScore[t];
        int r = 0;
        for (int j = 0; j < MM; ++j) {
            float sj = topScore[j];
            r += (sj > myS || (sj == myS && j < t)) ? 1 : 0;
        }
        slotCluster[r] = t;
        if (t == 0) {
            dirtyM[0][0] = 0xFFFFFFFFu; dirtyM[0][1] = 0xFFFFFFFFu;
            dirtyM[1][0] = 0u; dirtyM[1][1] = 0u;
            dirtyM[2][0] = 0u; dirtyM[2][1] = 0u;
        }
    }
    __syncthreads();

    // rank-ordered ownership: wave's slot q handles rank q*16+wid
    int cq[CPW];
#pragma unroll
    for (int q = 0; q < CPW; ++q) cq[q] = slotCluster[q * NW + wid];

    // ---- step 3: dirty-gated Jacobi rounds; parity state; stateless recompute ----
    int par = 0;
    for (int rr = 0; rr < 8200; ++rr) {
        const int cur = rr % 3, nxt = (rr + 1) % 3, clr = (rr + 2) % 3;
        const u64 dirty = ((u64)dirtyM[cur][1] << 32) | (u64)dirtyM[cur][0];
        if (dirty == 0ull) break;                    // uniform exit (post-barrier read)
        if (tid == 0) { dirtyM[clr][0] = 0u; dirtyM[clr][1] = 0u; }
        const int parN = par ^ 1;
#pragma unroll
        for (int q = 0; q < CPW; ++q) {
            const int cc = cq[q];
            if ((dirty >> cc) & 1ull) {
                DO_CLUSTER(cc);
            } else {
                COPY_CLUSTER(cc);
            }
        }
        __syncthreads();                             // single barrier per round
        par = parN;
    }

    // ---- step 4: loss = sum(kept scores)/count (reload keys via masks) ----
    float s = 0.f; int ccount = 0;
#pragma unroll
    for (int q = 0; q < CPW; ++q) {
        const int c = cq[q];
        u64 m0 = kMask0[par][c], m1 = kMask1[par][c];
        if ((m0 >> lane) & 1ull) s += keys[base + c * 128 + lane];
        if ((m1 >> lane) & 1ull) s += keys[base + c * 128 + 64 + lane];
        ccount += (int)__popcll(m0) + (int)__popcll(m1);
    }
    s = wave_sum64(s);
    if (lane == 0) { waveSum[wid] = s; waveCnt[wid] = ccount; }
    __syncthreads();
    if (tid == 0) {
        float tot = 0.f; int ct = 0;
#pragma unroll
        for (int w = 0; w < NW; ++w) { tot += waveSum[w]; ct += waveCnt[w]; }
        loss[b] = tot / (float)ct;               // 0/0 -> NaN matches reference
    }
}

extern "C" void kernel_launch(void* const* d_in, const int* in_sizes, int n_in,
                              void* d_out, int out_size, void* d_ws, size_t ws_size,
                              hipStream_t stream) {
    const float* outp = (const float*)d_in[0];   // (B, N, 85) f32
    const float* lab  = (const float*)d_in[1];   // (B, M, 5)  f32
    float* loss = (float*)d_out;                 // (1, B) f32

    float4* boxes = (float4*)d_ws;                                    // 2 MB
    float*  keys  = (float*)((char*)d_ws + (size_t)BB * NN * sizeof(float4));

    dim3 g1(BB, NN / NT1);
    prep_kernel<<<g1, NT1, 0, stream>>>(outp, lab, boxes, keys);
    nms_kernel<<<BB, NT2, 0, stream>>>(boxes, keys, loss);
}

// Round 18
// 54.535 us; speedup vs baseline: 1.1698x; 1.1698x over previous
//
#include <hip/hip_runtime.h>
#include <math.h>

#define BB 16
#define NN 8192
#define MM 64
#define ROW 85
#define EPS_F 1e-7f

#define NT1 256
#define NT2 1024         // 16 waves
#define NW  16
#define CPW 4            // clusters per wave
#define CAPB 8           // LDS-cached kept entries per cluster (overflow -> exact global walk)

typedef unsigned long long u64;

// ---------------- Kernel 1: boxes + masked score keys (cluster-permuted) ----------------
__global__ void prep_kernel(const float* __restrict__ outp,
                            const float* __restrict__ lab,
                            float4* __restrict__ boxes,
                            float* __restrict__ keys) {
    __shared__ float4 gbox[MM];
    __shared__ float garea[MM];
    const int b = blockIdx.x;
    const int tid = threadIdx.x;
    if (tid < MM) {
        const float* lr = lab + ((size_t)b * MM + tid) * 5;
        float cx = lr[1], cy = lr[2], w = lr[3], h = lr[4];
        float x1 = fminf(fmaxf(cx - w * 0.5f, 0.f), 1.f) * 640.f;
        float y1 = fminf(fmaxf(cy - h * 0.5f, 0.f), 1.f) * 640.f;
        float x2 = fminf(fmaxf(cx + w * 0.5f, 0.f), 1.f) * 640.f;
        float y2 = fminf(fmaxf(cy + h * 0.5f, 0.f), 1.f) * 640.f;
        gbox[tid] = make_float4(x1, y1, x2, y2);
        garea[tid] = (x2 - x1) * (y2 - y1);
    }
    __syncthreads();
    const int n = blockIdx.y * NT1 + tid;
    const float* row = outp + ((size_t)b * NN + n) * ROW;
    float cx = row[0], cy = row[1], w = row[2], h = row[3];
    float obj = row[4], c0 = row[5];
    float px1 = cx - w * 0.5f, py1 = cy - h * 0.5f;
    float px2 = cx + w * 0.5f, py2 = cy + h * 0.5f;
    float pa = (px2 - px1) * (py2 - py1);

    const int m0 = n & (MM - 1);
    bool match;
    {
        float4 g = gbox[m0];
        float iw = fmaxf(fminf(px2, g.z) - fmaxf(px1, g.x), 0.f);
        float ih = fmaxf(fminf(py2, g.w) - fmaxf(py1, g.y), 0.f);
        float inter = iw * ih;
        match = (inter / (garea[m0] + pa - inter) >= 0.5f);  // exact div as reference
    }
    if (!match) {
        for (int m = 0; m < MM; ++m) {
            float4 g = gbox[m];
            float iw = fmaxf(fminf(px2, g.z) - fmaxf(px1, g.x), 0.f);
            float ih = fmaxf(fminf(py2, g.w) - fmaxf(py1, g.y), 0.f);
            float inter = iw * ih;
            match = match || (inter / (garea[m] + pa - inter) >= 0.5f);
        }
    }
    bool valid = (obj >= 0.0f) && match;
    // cluster permutation: ppos = (n%64)*128 + n/64
    size_t bn = (size_t)b * NN + ((n & 63) * 128 + (n >> 6));
    boxes[bn] = make_float4(px1, py1, px2, py2);
    keys[bn] = valid ? (c0 * obj) : -INFINITY;
}

// ---------------- DPP wave folds (valid at lane 63) ----------------
__device__ __forceinline__ float wave_fold_max(float x) {
#define DPP_STEPX(ctrl)                                                          \
    { int _o = __builtin_amdgcn_update_dpp(__float_as_int(x), __float_as_int(x), \
                                           (ctrl), 0xF, 0xF, false);             \
      x = fmaxf(x, __int_as_float(_o)); }
    DPP_STEPX(0x111) DPP_STEPX(0x112) DPP_STEPX(0x114)
    DPP_STEPX(0x118) DPP_STEPX(0x142) DPP_STEPX(0x143)
#undef DPP_STEPX
    return x;
}
__device__ __forceinline__ float wave_fold_min(float x) {
#define DPP_STEPN(ctrl)                                                          \
    { int _o = __builtin_amdgcn_update_dpp(__float_as_int(x), __float_as_int(x), \
                                           (ctrl), 0xF, 0xF, false);             \
      x = fminf(x, __int_as_float(_o)); }
    DPP_STEPN(0x111) DPP_STEPN(0x112) DPP_STEPN(0x114)
    DPP_STEPN(0x118) DPP_STEPN(0x142) DPP_STEPN(0x143)
#undef DPP_STEPN
    return x;
}
__device__ __forceinline__ float wave_max64(float x) {
    return __int_as_float(__builtin_amdgcn_readlane(__float_as_int(wave_fold_max(x)), 63));
}
__device__ __forceinline__ float wave_sum64(float x) {
#define DPP_ADD(ctrl)                                                            \
    { int _o = __builtin_amdgcn_update_dpp(0, __float_as_int(x),                 \
                                           (ctrl), 0xF, 0xF, true);              \
      x += __int_as_float(_o); }
    DPP_ADD(0x111) DPP_ADD(0x112) DPP_ADD(0x114)
    DPP_ADD(0x118) DPP_ADD(0x142) DPP_ADD(0x143)
#undef DPP_ADD
    return __int_as_float(__builtin_amdgcn_readlane(__float_as_int(x), 63));
}
__device__ __forceinline__ float bcastlane(float v, int l) {
    return __int_as_float(__builtin_amdgcn_readlane(__float_as_int(v), l));
}

// kill test for one member slot vs kept box (sj, bj, hbj)
#define KILL_TEST(AK, K_)  do {                                                  \
    float _xx1 = fmaxf(bj.x, x1[K_]), _yy1 = fmaxf(bj.y, y1[K_]);                \
    float _xx2 = fminf(bj.z, x2[K_]), _yy2 = fminf(bj.w, y2[K_]);                \
    float _iw = fmaxf(_xx2 - _xx1 + 1.f, 0.f);                                   \
    float _ih = fmaxf(_yy2 - _yy1 + 1.f, 0.f);                                   \
    float _in = _iw * _ih;                                                       \
    if (sj > ps[K_] && 1.5f * _in > hbj + ha[K_]) (AK) = -INFINITY;              \
} while (0)

// ---------------- Kernel 2: Jacobi/GS fixed-point greedy NMS (single-buffer) ----------------
__global__ void __launch_bounds__(NT2)
nms_kernel(const float4* __restrict__ boxes, const float* __restrict__ keys,
           float* __restrict__ loss) {
    __shared__ float4 clusterBB[MM];
    __shared__ float  clusterMinA[MM];
    __shared__ u64    adjL[MM];
    __shared__ float4 keptBoxL[MM][CAPB];      // 8 KB
    __shared__ float2 keptMetaL[MM][CAPB];     // 4 KB  (score, halfArea+eps/2)
    __shared__ u64    kMask0[MM];              // 512 B
    __shared__ u64    kMask1[MM];              // 512 B
    __shared__ int    keptCnt[MM];
    __shared__ unsigned int chMask[3][2];      // rotating changed masks
    __shared__ float  waveSum[NW];
    __shared__ int    waveCnt[NW];

    const int b = blockIdx.x;
    const int tid = threadIdx.x;
    const int wid = tid >> 6;
    const int lane = tid & 63;
    const size_t base = (size_t)b * NN;

    // pristine per-thread state: 4 clusters x 2 slots (static indexing via unroll)
    float x1[8], y1[8], x2[8], y2[8], ha[8], ps[8];
#pragma unroll
    for (int q = 0; q < CPW; ++q) {
#pragma unroll
        for (int s = 0; s < 2; ++s) {
            const int k = q * 2 + s;
            const int c = CPW * wid + q;
            int idx = c * 128 + s * 64 + lane;
            float4 bb = boxes[base + idx];
            x1[k] = bb.x; y1[k] = bb.y; x2[k] = bb.z; y2[k] = bb.w;
            ps[k] = keys[base + idx];
            ha[k] = 0.5f * ((x2[k] - x1[k] + 1.f) * (y2[k] - y1[k] + 1.f));
        }
    }

    // step 1: per-cluster valid bbox + min area
#pragma unroll
    for (int q = 0; q < CPW; ++q) {
        const int k0 = 2 * q, k1 = 2 * q + 1;
        float mx = INFINITY, my = INFINITY, Mx = -INFINITY, My = -INFINITY, mA = INFINITY;
        if (ps[k0] != -INFINITY) { mx = x1[k0]; my = y1[k0]; Mx = x2[k0]; My = y2[k0]; mA = 2.f * ha[k0]; }
        if (ps[k1] != -INFINITY) { mx = fminf(mx, x1[k1]); my = fminf(my, y1[k1]);
                                   Mx = fmaxf(Mx, x2[k1]); My = fmaxf(My, y2[k1]);
                                   mA = fminf(mA, 2.f * ha[k1]); }
        mx = wave_fold_min(mx); my = wave_fold_min(my);
        Mx = wave_fold_max(Mx); My = wave_fold_max(My);
        mA = wave_fold_min(mA);
        if (lane == 63) {
            clusterBB[CPW * wid + q] = make_float4(mx, my, Mx, My);
            clusterMinA[CPW * wid + q] = mA;
        }
    }
    __syncthreads();

    // step 2 (wave 0): conservative cluster adjacency + state init
    if (wid == 0) {
        const int t = lane;
        float4 bbT = clusterBB[t];
        float  maT = clusterMinA[t];
        u64 adj = 0ull;
        for (int j = 0; j < MM; ++j) {
            float4 bbJ = clusterBB[j];
            float  maJ = clusterMinA[j];
            float iw = fminf(bbT.z, bbJ.z) - fmaxf(bbT.x, bbJ.x) + 1.f;
            float ih = fminf(bbT.w, bbJ.w) - fmaxf(bbT.y, bbJ.y) + 1.f;
            if (j != t && iw > 0.f && ih > 0.f) {
                float I = iw * ih;
                // IoU>0.5 between members impossible if 3I < aI+aJ or 2I < max(aI,aJ)
                bool noe = (3.f * I < maT + maJ) || (2.f * I < fmaxf(maT, maJ));
                if (!noe) adj |= (1ull << j);
            }
        }
        adjL[t] = adj;
        kMask0[t] = 0ull; kMask1[t] = 0ull;
        keptCnt[t] = 0;
        if (t == 0) {
            chMask[0][0] = 0xFFFFFFFFu; chMask[0][1] = 0xFFFFFFFFu;
            chMask[1][0] = 0u; chMask[1][1] = 0u;
            chMask[2][0] = 0u; chMask[2][1] = 0u;
        }
    }
    __syncthreads();

    // step 3: fixed-point rounds (single buffer; unique fixed point => exact greedy)
    int rr = 0;
    for (; rr < 8200; ++rr) {
        const int cur = rr % 3, nxt = (rr + 1) % 3, clr = (rr + 2) % 3;
        const u64 cm = ((u64)chMask[cur][1] << 32) | (u64)chMask[cur][0];
        if (cm == 0ull) break;                       // uniform exit (post-barrier read)
        if (tid == 0) { chMask[clr][0] = 0u; chMask[clr][1] = 0u; }
#pragma unroll
        for (int q = 0; q < CPW; ++q) {
            const int c = CPW * wid + q;
            if (((adjL[c] | (1ull << c)) & cm) == 0ull) continue;

            u64 om0 = kMask0[c], om1 = kMask1[c];    // old state (owner-local read)
            float a0 = ps[2 * q], a1 = ps[2 * q + 1];
            float4 CBc = clusterBB[c];
            float mha = 0.5f * clusterMinA[c];

            // ---- lane-parallel screen: lane L examines neighbor cluster L ----
            bool flag = false;
            {
                const u64 adjc = adjL[c];
                if ((adjc >> lane) & 1ull) {
                    int K = keptCnt[lane];
                    if (K > CAPB) flag = true;       // overflow must take exact path
                    int KB = K < CAPB ? K : CAPB;
                    for (int t2 = 0; t2 < KB; ++t2) {
                        float4 bj = keptBoxL[lane][t2];
                        float2 mt = keptMetaL[lane][t2];
                        float iwS = fminf(bj.z, CBc.z) - fmaxf(bj.x, CBc.x) + 1.f;
                        float ihS = fminf(bj.w, CBc.w) - fmaxf(bj.y, CBc.y) + 1.f;
                        if (iwS > 0.f && ihS > 0.f && 1.5f * (iwS * ihS) > mt.y + mha)
                            flag = true;
                    }
                }
            }
            u64 passM = __ballot(flag);

            // ---- serial walk over passing neighbors only ----
            while (passM) {
                int ac = __ffsll(passM) - 1; passM &= (passM - 1);
                int K = keptCnt[ac];
                int KB = K < CAPB ? K : CAPB;
                for (int t2 = 0; t2 < KB; ++t2) {
                    float4 bj = keptBoxL[ac][t2];
                    float2 mt = keptMetaL[ac][t2];
                    float iwS = fminf(bj.z, CBc.z) - fmaxf(bj.x, CBc.x) + 1.f;
                    float ihS = fminf(bj.w, CBc.w) - fmaxf(bj.y, CBc.y) + 1.f;
                    if (iwS > 0.f && ihS > 0.f && 1.5f * (iwS * ihS) > mt.y + mha) {
                        float sj = mt.x, hbj = mt.y;
                        KILL_TEST(a0, 2 * q);
                        KILL_TEST(a1, 2 * q + 1);
                    }
                }
                if (K > CAPB) {                      // exact overflow (rare)
                    u64 mm = kMask0[ac];
                    while (mm) {
                        int bit = __ffsll(mm) - 1; mm &= (mm - 1);
                        int gi = ac * 128 + bit;
                        float4 bj = boxes[base + gi];
                        float sj = keys[base + gi];
                        float hbj = 0.5f * ((bj.z - bj.x + 1.f) * (bj.w - bj.y + 1.f))
                                    + 0.5f * EPS_F;
                        KILL_TEST(a0, 2 * q);
                        KILL_TEST(a1, 2 * q + 1);
                    }
                    mm = kMask1[ac];
                    while (mm) {
                        int bit = __ffsll(mm) - 1; mm &= (mm - 1);
                        int gi = ac * 128 + 64 + bit;
                        float4 bj = boxes[base + gi];
                        float sj = keys[base + gi];
                        float hbj = 0.5f * ((bj.z - bj.x + 1.f) * (bj.w - bj.y + 1.f))
                                    + 0.5f * EPS_F;
                        KILL_TEST(a0, 2 * q);
                        KILL_TEST(a1, 2 * q + 1);
                    }
                }
            }

            // ---- local serial greedy (wave-local, no barriers) ----
            bool kept0 = false, kept1 = false;
            int cnt = 0;
            while (true) {
                float lv = fmaxf(a0, a1);
                float wm = wave_max64(lv);
                if (wm == -INFINITY) break;
                u64 bm = __ballot(lv == wm);
                int wl = __ffsll(bm) - 1;
                int la = (a0 == lv) ? 0 : 1;
                float cxa = la ? x1[2 * q + 1] : x1[2 * q];
                float cya = la ? y1[2 * q + 1] : y1[2 * q];
                float cxb = la ? x2[2 * q + 1] : x2[2 * q];
                float cyb = la ? y2[2 * q + 1] : y2[2 * q];
                float cha = la ? ha[2 * q + 1] : ha[2 * q];
                float bx1 = bcastlane(cxa, wl), by1 = bcastlane(cya, wl);
                float bx2 = bcastlane(cxb, wl), by2 = bcastlane(cyb, wl);
                float hcb = bcastlane(cha, wl) + 0.5f * EPS_F;
                if (lane == wl) {
                    if (cnt < CAPB) {
                        keptBoxL[c][cnt] = make_float4(cxa, cya, cxb, cyb);
                        keptMetaL[c][cnt] = make_float2(lv, cha + 0.5f * EPS_F);
                    }
                    if (la == 0) { kept0 = true; a0 = -INFINITY; }
                    else         { kept1 = true; a1 = -INFINITY; }
                }
                cnt++;
                if (a0 != -INFINITY) {
                    const int k = 2 * q;
                    float xx1 = fmaxf(bx1, x1[k]), yy1 = fmaxf(by1, y1[k]);
                    float xx2 = fminf(bx2, x2[k]), yy2 = fminf(by2, y2[k]);
                    float iw = fmaxf(xx2 - xx1 + 1.f, 0.f);
                    float ih = fmaxf(yy2 - yy1 + 1.f, 0.f);
                    if (1.5f * (iw * ih) > hcb + ha[k]) a0 = -INFINITY;
                }
                if (a1 != -INFINITY) {
                    const int k = 2 * q + 1;
                    float xx1 = fmaxf(bx1, x1[k]), yy1 = fmaxf(by1, y1[k]);
                    float xx2 = fminf(bx2, x2[k]), yy2 = fminf(by2, y2[k]);
                    float iw = fmaxf(xx2 - xx1 + 1.f, 0.f);
                    float ih = fmaxf(yy2 - yy1 + 1.f, 0.f);
                    if (1.5f * (iw * ih) > hcb + ha[k]) a1 = -INFINITY;
                }
            }
            u64 m0 = __ballot(kept0);
            u64 m1 = __ballot(kept1);
            if (lane == 0) {
                kMask0[c] = m0; kMask1[c] = m1; keptCnt[c] = cnt;
                if (m0 != om0 || m1 != om1)
                    atomicOr(&chMask[nxt][c >> 5], 1u << (c & 31));
            }
        }
        __syncthreads();                             // single barrier per round
    }

    // step 4: loss = sum(kept scores)/count, read from pristine registers via masks
    float s = 0.f; int ccount = 0;
#pragma unroll
    for (int q = 0; q < CPW; ++q) {
        const int c = CPW * wid + q;
        u64 m0 = kMask0[c], m1 = kMask1[c];
        if ((m0 >> lane) & 1ull) s += ps[2 * q];
        if ((m1 >> lane) & 1ull) s += ps[2 * q + 1];
        ccount += (int)__popcll(m0) + (int)__popcll(m1);
    }
    s = wave_sum64(s);
    if (lane == 0) { waveSum[wid] = s; waveCnt[wid] = ccount; }
    __syncthreads();
    if (tid == 0) {
        float tot = 0.f; int ct = 0;
#pragma unroll
        for (int w = 0; w < NW; ++w) { tot += waveSum[w]; ct += waveCnt[w]; }
        loss[b] = tot / (float)ct;               // 0/0 -> NaN matches reference
    }
}

extern "C" void kernel_launch(void* const* d_in, const int* in_sizes, int n_in,
                              void* d_out, int out_size, void* d_ws, size_t ws_size,
                              hipStream_t stream) {
    const float* outp = (const float*)d_in[0];   // (B, N, 85) f32
    const float* lab  = (const float*)d_in[1];   // (B, M, 5)  f32
    float* loss = (float*)d_out;                 // (1, B) f32

    float4* boxes = (float4*)d_ws;                                    // 2 MB
    float*  keys  = (float*)((char*)d_ws + (size_t)BB * NN * sizeof(float4));

    dim3 g1(BB, NN / NT1);
    prep_kernel<<<g1, NT1, 0, stream>>>(outp, lab, boxes, keys);
    nms_kernel<<<BB, NT2, 0, stream>>>(boxes, keys, loss);
}